// Round 4
// baseline (3496.392 us; speedup 1.0000x reference)
//
#include <hip/hip_runtime.h>

// GCN autoencoder, fp32, CSR gather-based.
// R3: block-owned 64-node tiles; edges accumulated into LDS via ds_add_f32
// (workgroup-scope fp32 atomics); quarter-wave float4 gathers, unrolled x4;
// epilogue matvec with W-columns in registers + broadcast ds_read_b128.

static inline size_t align256(size_t x) { return (x + 255) & ~(size_t)255; }

__global__ void hist_kernel(const int* __restrict__ dst, int E, int* __restrict__ cnt) {
    int e = blockIdx.x * blockDim.x + threadIdx.x;
    if (e < E) atomicAdd(&cnt[dst[e]], 1);
}

__global__ void dinv_kernel(const int* __restrict__ cnt, float* __restrict__ dinv, int n) {
    int i = blockIdx.x * blockDim.x + threadIdx.x;
    if (i < n) dinv[i] = rsqrtf((float)cnt[i] + 1.0f);  // +1 self loop
}

// Single-block exclusive scan: row_ptr[0]=0, row_ptr[i+1]=sum(cnt[0..i]).
__global__ void scan_kernel(const int* __restrict__ cnt, int* __restrict__ row_ptr, int n) {
    __shared__ int wsum[16];
    __shared__ int carry;
    int tid = threadIdx.x, lane = tid & 63, wv = tid >> 6;
    if (tid == 0) { carry = 0; row_ptr[0] = 0; }
    __syncthreads();
    for (int base = 0; base < n; base += 1024) {
        int idx = base + tid;
        int v = (idx < n) ? cnt[idx] : 0;
        int x = v;
#pragma unroll
        for (int off = 1; off < 64; off <<= 1) {
            int t = __shfl_up(x, off, 64);
            if (lane >= off) x += t;
        }
        if (lane == 63) wsum[wv] = x;
        __syncthreads();
        if (wv == 0 && lane < 16) {
            int s = wsum[lane];
#pragma unroll
            for (int off = 1; off < 16; off <<= 1) {
                int t = __shfl_up(s, off, 16);
                if ((lane & 15) >= off) s += t;
            }
            wsum[lane] = s;
        }
        __syncthreads();
        int waveoff = (wv == 0) ? 0 : wsum[wv - 1];
        if (idx < n) row_ptr[idx + 1] = carry + waveoff + x;
        __syncthreads();
        if (tid == 0) carry += wsum[15];
        __syncthreads();
    }
}

// CSR record: (src, dst&63, weight_bits, unused)
__global__ void scatter_kernel(const int* __restrict__ src, const int* __restrict__ dst, int E,
                               const int* __restrict__ row_ptr, int* __restrict__ cur,
                               const float* __restrict__ dinv,
                               int4* __restrict__ csr) {
    int e = blockIdx.x * blockDim.x + threadIdx.x;
    if (e >= E) return;
    int s = src[e], d = dst[e];
    int pos = row_ptr[d] + atomicAdd(&cur[d], 1);
    csr[pos] = make_int4(s, d & 63, __float_as_int(dinv[s] * dinv[d]), 0);
}

// Wave-per-node matmul (layer 3 pre-agg shrink 64->32).
template <int K, int M>
__global__ void matmul_kernel(const float* __restrict__ in, const float* __restrict__ W,
                              float* __restrict__ out, int n) {
    __shared__ float Ws[K * M];
    for (int t = threadIdx.x; t < K * M; t += blockDim.x) Ws[t] = W[t];
    __syncthreads();
    int wave = threadIdx.x >> 6, lane = threadIdx.x & 63;
    int node = blockIdx.x * (blockDim.x >> 6) + wave;
    if (node >= n) return;
    float x = (lane < K) ? in[(size_t)node * K + lane] : 0.0f;
    int j = lane & (M - 1);
    float acc = 0.0f;
#pragma unroll
    for (int k = 0; k < K; ++k) acc = fmaf(__shfl(x, k, 64), Ws[k * M + j], acc);
    if (lane < M) out[(size_t)node * M + lane] = acc;
}

__device__ __forceinline__ void lds_add(float* p, float v) {
    __hip_atomic_fetch_add(p, v, __ATOMIC_RELAXED, __HIP_MEMORY_SCOPE_WORKGROUP);
}

// Block owns 64 nodes. LDS acc rows (padded to SP float4s). Edge phase: each
// K/4-lane group handles one edge (broadcast int4 record, float4 gather,
// 4x ds_add_f32). Epilogue: W columns in registers, acc via broadcast b128.
template <int K, int M, bool RELU, bool HAS_W>
__global__ void __launch_bounds__(256, 4) fused_layer_lds(
        const float* __restrict__ in, const float* __restrict__ W,
        const float* __restrict__ bias,
        const int* __restrict__ row_ptr, const int4* __restrict__ csr,
        const float* __restrict__ dinv,
        float* __restrict__ out, int n) {
    constexpr int LPR = K / 4;       // lanes per row (float4 cols)
    constexpr int SP  = LPR + 1;     // row stride in float4 (pad)
    constexpr int NPB = 64;          // nodes per block
    __shared__ alignas(16) float accF[NPB * SP * 4];
    const float4* acc4 = (const float4*)accF;

    const int i0 = blockIdx.x * NPB;
    const int nnodes = min(NPB, n - i0);
    const float4* in4 = (const float4*)in;

    // init acc rows with self-loop term dinv^2 * in[i]
    for (int idx = threadIdx.x; idx < nnodes * LPR; idx += 256) {
        int nl = idx / LPR, s = idx % LPR;
        float di = dinv[i0 + nl];
        float w2 = di * di;
        float4 v = in4[(size_t)(i0 + nl) * LPR + s];
        *(float4*)&accF[(nl * SP + s) * 4] = make_float4(v.x * w2, v.y * w2, v.z * w2, v.w * w2);
    }
    __syncthreads();

    // edge accumulation
    const int e0 = row_ptr[i0];
    const int e1 = row_ptr[i0 + nnodes];
    const int NQ = 256 / LPR;                 // edge groups per block
    const int qw = threadIdx.x / LPR;
    const int sub = threadIdx.x % LPR;

#define EDGE_BODY(EE) { \
        int4 r = csr[(EE)]; \
        float ww = __int_as_float(r.z); \
        float4 v = in4[(size_t)r.x * LPR + sub]; \
        float* rowp = accF + r.y * (SP * 4) + sub * 4; \
        lds_add(rowp + 0, ww * v.x); \
        lds_add(rowp + 1, ww * v.y); \
        lds_add(rowp + 2, ww * v.z); \
        lds_add(rowp + 3, ww * v.w); }

    int e = e0 + qw;
    for (; e + 3 * NQ < e1; e += 4 * NQ) {
        EDGE_BODY(e)
        EDGE_BODY(e + NQ)
        EDGE_BODY(e + 2 * NQ)
        EDGE_BODY(e + 3 * NQ)
    }
    for (; e < e1; e += NQ) EDGE_BODY(e)
#undef EDGE_BODY
    __syncthreads();

    // epilogue
    const int wv = threadIdx.x >> 6;
    const int lane = threadIdx.x & 63;
    if (HAS_W) {
        const int j = lane & (M - 1);
        float wcol[K];
#pragma unroll
        for (int k = 0; k < K; ++k) wcol[k] = W[k * M + j];
        const float br = bias[j];
        for (int nl = wv; nl < nnodes; nl += 8) {   // two nodes in flight
            int nl2 = nl + 4;
            bool has2 = nl2 < nnodes;
            int nlb = has2 ? nl2 : nl;
            float y0 = br, y1 = br;
#pragma unroll
            for (int s = 0; s < LPR; ++s) {
                float4 a0 = acc4[nl * SP + s];
                float4 a1 = acc4[nlb * SP + s];
                y0 = fmaf(a0.x, wcol[4 * s + 0], y0);
                y1 = fmaf(a1.x, wcol[4 * s + 0], y1);
                y0 = fmaf(a0.y, wcol[4 * s + 1], y0);
                y1 = fmaf(a1.y, wcol[4 * s + 1], y1);
                y0 = fmaf(a0.z, wcol[4 * s + 2], y0);
                y1 = fmaf(a1.z, wcol[4 * s + 2], y1);
                y0 = fmaf(a0.w, wcol[4 * s + 3], y0);
                y1 = fmaf(a1.w, wcol[4 * s + 3], y1);
            }
            if (RELU) { y0 = fmaxf(y0, 0.0f); y1 = fmaxf(y1, 0.0f); }
            if (lane < M) {
                out[(size_t)(i0 + nl) * M + j] = y0;
                if (has2) out[(size_t)(i0 + nl2) * M + j] = y1;
            }
        }
    } else {
        // K == M: add bias, write rows cooperatively
        const float4* bias4 = (const float4*)bias;
        float4* out4 = (float4*)out;
        for (int idx = threadIdx.x; idx < nnodes * LPR; idx += 256) {
            int nl = idx / LPR, s = idx % LPR;
            float4 a = acc4[nl * SP + s];
            float4 b = bias4[s];
            float4 v = make_float4(a.x + b.x, a.y + b.y, a.z + b.z, a.w + b.w);
            if (RELU) {
                v.x = fmaxf(v.x, 0.f); v.y = fmaxf(v.y, 0.f);
                v.z = fmaxf(v.z, 0.f); v.w = fmaxf(v.w, 0.f);
            }
            out4[(size_t)(i0 + nl) * LPR + s] = v;
        }
    }
}

extern "C" void kernel_launch(void* const* d_in, const int* in_sizes, int n_in,
                              void* d_out, int out_size, void* d_ws, size_t ws_size,
                              hipStream_t stream) {
    (void)n_in; (void)out_size; (void)ws_size;

    const float* x  = (const float*)d_in[0];
    const int*   ei = (const int*)d_in[1];
    const float* W1 = (const float*)d_in[2];  const float* b1 = (const float*)d_in[3];
    const float* W2 = (const float*)d_in[4];  const float* b2 = (const float*)d_in[5];
    const float* W3 = (const float*)d_in[6];  const float* b3 = (const float*)d_in[7];
    const float* W4 = (const float*)d_in[8];  const float* b4 = (const float*)d_in[9];
    const float* W5 = (const float*)d_in[10]; const float* b5 = (const float*)d_in[11];
    const float* W6 = (const float*)d_in[12]; const float* b6 = (const float*)d_in[13];

    const int n = in_sizes[0] / 64;   // 100000
    const int E = in_sizes[1] / 2;    // 1600000
    const int* src = ei;
    const int* dst = ei + E;

    float* out  = (float*)d_out;
    float* xrec = out;                       // [n,64]
    float* z    = out + (size_t)n * 64;      // [n,32]

    char* ws = (char*)d_ws;
    size_t off = 0;
    float* dinv    = (float*)(ws + off); off += align256((size_t)n * 4);
    int*   cnt     = (int*)(ws + off);   off += align256((size_t)n * 4);
    int*   row_ptr = (int*)(ws + off);   off += align256((size_t)(n + 1) * 4);
    int*   cur     = (int*)(ws + off);   off += align256((size_t)n * 4);
    int4*  csr     = (int4*)(ws + off);  off += align256((size_t)E * 16);
    float* buf1    = (float*)(ws + off); off += align256((size_t)n * 64 * 4);
    float* buf2    = (float*)(ws + off); off += align256((size_t)n * 64 * 4);
    float* mm32    = buf1;  // 32-wide temp reuses buf1 between L2 and L4

    const int B = 256;
    const int edgeGrid = (E + B - 1) / B;
    const int tileGrid = (n + 63) / 64;

    // ---- CSR build ----
    hipMemsetAsync(cnt, 0, (size_t)n * 4, stream);
    hist_kernel<<<edgeGrid, B, 0, stream>>>(dst, E, cnt);
    dinv_kernel<<<(n + B - 1) / B, B, 0, stream>>>(cnt, dinv, n);
    scan_kernel<<<1, 1024, 0, stream>>>(cnt, row_ptr, n);
    hipMemsetAsync(cur, 0, (size_t)n * 4, stream);
    scatter_kernel<<<edgeGrid, B, 0, stream>>>(src, dst, E, row_ptr, cur, dinv, csr);

    // ---- Layer 1: (A x) W1 + b1, relu -> buf2 ----
    fused_layer_lds<64, 64, true, true><<<tileGrid, B, 0, stream>>>(
        x, W1, b1, row_ptr, csr, dinv, buf2, n);
    // ---- Layer 2: -> buf1 (frees buf2 after) ----
    fused_layer_lds<64, 64, true, true><<<tileGrid, B, 0, stream>>>(
        buf2, W2, b2, row_ptr, csr, dinv, buf1, n);
    // ---- Layer 3: mm = buf1 @ W3 (64->32) -> buf2, then A mm + b3 -> z ----
    matmul_kernel<64, 32><<<(n + 3) / 4, B, 0, stream>>>(buf1, W3, buf2, n);
    fused_layer_lds<32, 32, false, false><<<tileGrid, B, 0, stream>>>(
        buf2, nullptr, b3, row_ptr, csr, dinv, z, n);
    // ---- Layer 4: (A z) W4 + b4, relu -> buf1 (aggregate at 32 wide) ----
    fused_layer_lds<32, 64, true, true><<<tileGrid, B, 0, stream>>>(
        z, W4, b4, row_ptr, csr, dinv, buf1, n);
    // ---- Layer 5: -> buf2 ----
    fused_layer_lds<64, 64, true, true><<<tileGrid, B, 0, stream>>>(
        buf1, W5, b5, row_ptr, csr, dinv, buf2, n);
    // ---- Layer 6 (no relu) -> xrec ----
    fused_layer_lds<64, 64, false, true><<<tileGrid, B, 0, stream>>>(
        buf2, W6, b6, row_ptr, csr, dinv, xrec, n);
    (void)mm32;
}

// Round 5
// 912.992 us; speedup vs baseline: 3.8296x; 3.8296x over previous
//
#include <hip/hip_runtime.h>

// GCN autoencoder, fp32, CSR gather-based.
// R4: back to register accumulation (R2 skeleton). Edge loop: direct broadcast
// record loads (no shfl in the chain), 4-deep batched float4 gathers for MLP.
// Grid-stride 8 nodes/wave; epilogue matvec with W columns in registers and
// the aggregated row staged via per-wave LDS (1 write + 16 broadcast b128 reads).

static inline size_t align256(size_t x) { return (x + 255) & ~(size_t)255; }

__global__ void hist_kernel(const int* __restrict__ dst, int E, int* __restrict__ cnt) {
    int e = blockIdx.x * blockDim.x + threadIdx.x;
    if (e < E) atomicAdd(&cnt[dst[e]], 1);
}

__global__ void dinv_kernel(const int* __restrict__ cnt, float* __restrict__ dinv, int n) {
    int i = blockIdx.x * blockDim.x + threadIdx.x;
    if (i < n) dinv[i] = rsqrtf((float)cnt[i] + 1.0f);  // +1 self loop
}

// Single-block exclusive scan: row_ptr[0]=0, row_ptr[i+1]=sum(cnt[0..i]).
__global__ void scan_kernel(const int* __restrict__ cnt, int* __restrict__ row_ptr, int n) {
    __shared__ int wsum[16];
    __shared__ int carry;
    int tid = threadIdx.x, lane = tid & 63, wv = tid >> 6;
    if (tid == 0) { carry = 0; row_ptr[0] = 0; }
    __syncthreads();
    for (int base = 0; base < n; base += 1024) {
        int idx = base + tid;
        int v = (idx < n) ? cnt[idx] : 0;
        int x = v;
#pragma unroll
        for (int off = 1; off < 64; off <<= 1) {
            int t = __shfl_up(x, off, 64);
            if (lane >= off) x += t;
        }
        if (lane == 63) wsum[wv] = x;
        __syncthreads();
        if (wv == 0 && lane < 16) {
            int s = wsum[lane];
#pragma unroll
            for (int off = 1; off < 16; off <<= 1) {
                int t = __shfl_up(s, off, 16);
                if ((lane & 15) >= off) s += t;
            }
            wsum[lane] = s;
        }
        __syncthreads();
        int waveoff = (wv == 0) ? 0 : wsum[wv - 1];
        if (idx < n) row_ptr[idx + 1] = carry + waveoff + x;
        __syncthreads();
        if (tid == 0) carry += wsum[15];
        __syncthreads();
    }
}

__global__ void scatter_kernel(const int* __restrict__ src, const int* __restrict__ dst, int E,
                               const int* __restrict__ row_ptr, int* __restrict__ cur,
                               const float* __restrict__ dinv,
                               int2* __restrict__ csr) {
    int e = blockIdx.x * blockDim.x + threadIdx.x;
    if (e >= E) return;
    int s = src[e], d = dst[e];
    int pos = row_ptr[d] + atomicAdd(&cur[d], 1);
    csr[pos] = make_int2(s, __float_as_int(dinv[s] * dinv[d]));
}

// Wave-per-node matmul (layer 3 pre-agg shrink 64->32).
template <int K, int M>
__global__ void matmul_kernel(const float* __restrict__ in, const float* __restrict__ W,
                              float* __restrict__ out, int n) {
    __shared__ float Ws[K * M];
    for (int t = threadIdx.x; t < K * M; t += blockDim.x) Ws[t] = W[t];
    __syncthreads();
    int wave = threadIdx.x >> 6, lane = threadIdx.x & 63;
    int node = blockIdx.x * (blockDim.x >> 6) + wave;
    if (node >= n) return;
    float x = (lane < K) ? in[(size_t)node * K + lane] : 0.0f;
    int j = lane & (M - 1);
    float acc = 0.0f;
#pragma unroll
    for (int k = 0; k < K; ++k) acc = fmaf(__shfl(x, k, 64), Ws[k * M + j], acc);
    if (lane < M) out[(size_t)node * M + lane] = acc;
}

// Fused aggregate(+matmul) layer, R4 structure.
// K: input width, M: output width (M==K if !HAS_W; M==64 if HAS_W).
template <int K, int M, bool RELU, bool HAS_W, int NPW>
__global__ void __launch_bounds__(256) fused_layer2(
        const float* __restrict__ in, const float* __restrict__ W,
        const float* __restrict__ bias,
        const int* __restrict__ row_ptr, const int2* __restrict__ csr,
        const float* __restrict__ dinv,
        float* __restrict__ out, int n) {
    constexpr int LPR = K / 4;        // lanes per row (float4 cols)
    constexpr int EPW = 64 / LPR;     // edges per wave-load
    constexpr int BATCH = 4 * EPW;    // edges per unrolled iter
    __shared__ float aS[4][K + 4];    // per-wave row staging (pad)

    const int wv = threadIdx.x >> 6, lane = threadIdx.x & 63;
    const int g = lane / LPR, sub = lane % LPR;
    const float4* in4 = (const float4*)in;

    // per-wave W columns + bias (amortized over NPW nodes)
    float wcol[HAS_W ? K : 1];
    float br = 0.0f;
    if (HAS_W) {
        const int j = lane & (M - 1);
#pragma unroll
        for (int k = 0; k < K; ++k) wcol[k] = W[k * M + j];
        br = bias[j];
    }

    const int wave_id = blockIdx.x * 4 + wv;
    const int i_lo = wave_id * NPW;
    const int i_hi = min(i_lo + NPW, n);

    for (int i = i_lo; i < i_hi; ++i) {
        const int beg = row_ptr[i], end = row_ptr[i + 1];
        float4 acc = make_float4(0.f, 0.f, 0.f, 0.f);
        if (g == 0) {  // self-loop term, counted once after butterfly
            float di = dinv[i];
            float w2 = di * di;
            float4 v = in4[(size_t)i * LPR + sub];
            acc = make_float4(v.x * w2, v.y * w2, v.z * w2, v.w * w2);
        }

        int e = beg;
        for (; e + BATCH <= end; e += BATCH) {
            int2 r0 = csr[e + 0 * EPW + g];
            int2 r1 = csr[e + 1 * EPW + g];
            int2 r2 = csr[e + 2 * EPW + g];
            int2 r3 = csr[e + 3 * EPW + g];
            float4 v0 = in4[(size_t)r0.x * LPR + sub];
            float4 v1 = in4[(size_t)r1.x * LPR + sub];
            float4 v2 = in4[(size_t)r2.x * LPR + sub];
            float4 v3 = in4[(size_t)r3.x * LPR + sub];
            float w0 = __int_as_float(r0.y), w1 = __int_as_float(r1.y);
            float w2 = __int_as_float(r2.y), w3 = __int_as_float(r3.y);
            acc.x = fmaf(w0, v0.x, acc.x); acc.y = fmaf(w0, v0.y, acc.y);
            acc.z = fmaf(w0, v0.z, acc.z); acc.w = fmaf(w0, v0.w, acc.w);
            acc.x = fmaf(w1, v1.x, acc.x); acc.y = fmaf(w1, v1.y, acc.y);
            acc.z = fmaf(w1, v1.z, acc.z); acc.w = fmaf(w1, v1.w, acc.w);
            acc.x = fmaf(w2, v2.x, acc.x); acc.y = fmaf(w2, v2.y, acc.y);
            acc.z = fmaf(w2, v2.z, acc.z); acc.w = fmaf(w2, v2.w, acc.w);
            acc.x = fmaf(w3, v3.x, acc.x); acc.y = fmaf(w3, v3.y, acc.y);
            acc.z = fmaf(w3, v3.z, acc.z); acc.w = fmaf(w3, v3.w, acc.w);
        }
        for (; e < end; e += EPW) {
            int idx = e + g;
            bool val = idx < end;
            int2 r = csr[val ? idx : beg];
            float ww = val ? __int_as_float(r.y) : 0.0f;
            float4 v = in4[(size_t)r.x * LPR + sub];
            acc.x = fmaf(ww, v.x, acc.x); acc.y = fmaf(ww, v.y, acc.y);
            acc.z = fmaf(ww, v.z, acc.z); acc.w = fmaf(ww, v.w, acc.w);
        }

        // butterfly reduce across edge-groups (all lanes end with the sum)
#pragma unroll
        for (int off = LPR; off < 64; off <<= 1) {
            acc.x += __shfl_xor(acc.x, off, 64);
            acc.y += __shfl_xor(acc.y, off, 64);
            acc.z += __shfl_xor(acc.z, off, 64);
            acc.w += __shfl_xor(acc.w, off, 64);
        }

        if (HAS_W) {
            if (g == 0) *(float4*)&aS[wv][sub * 4] = acc;
            float y = br;
#pragma unroll
            for (int s = 0; s < LPR; ++s) {
                float4 a = *(const float4*)&aS[wv][s * 4];
                y = fmaf(a.x, wcol[4 * s + 0], y);
                y = fmaf(a.y, wcol[4 * s + 1], y);
                y = fmaf(a.z, wcol[4 * s + 2], y);
                y = fmaf(a.w, wcol[4 * s + 3], y);
            }
            if (RELU) y = fmaxf(y, 0.0f);
            if (lane < M) out[(size_t)i * M + lane] = y;
        } else {
            if (g == 0) {
                float4 bb = ((const float4*)bias)[sub];
                float4 y = make_float4(acc.x + bb.x, acc.y + bb.y,
                                       acc.z + bb.z, acc.w + bb.w);
                if (RELU) {
                    y.x = fmaxf(y.x, 0.f); y.y = fmaxf(y.y, 0.f);
                    y.z = fmaxf(y.z, 0.f); y.w = fmaxf(y.w, 0.f);
                }
                ((float4*)out)[(size_t)i * LPR + sub] = y;
            }
        }
    }
}

extern "C" void kernel_launch(void* const* d_in, const int* in_sizes, int n_in,
                              void* d_out, int out_size, void* d_ws, size_t ws_size,
                              hipStream_t stream) {
    (void)n_in; (void)out_size; (void)ws_size;

    const float* x  = (const float*)d_in[0];
    const int*   ei = (const int*)d_in[1];
    const float* W1 = (const float*)d_in[2];  const float* b1 = (const float*)d_in[3];
    const float* W2 = (const float*)d_in[4];  const float* b2 = (const float*)d_in[5];
    const float* W3 = (const float*)d_in[6];  const float* b3 = (const float*)d_in[7];
    const float* W4 = (const float*)d_in[8];  const float* b4 = (const float*)d_in[9];
    const float* W5 = (const float*)d_in[10]; const float* b5 = (const float*)d_in[11];
    const float* W6 = (const float*)d_in[12]; const float* b6 = (const float*)d_in[13];

    const int n = in_sizes[0] / 64;   // 100000
    const int E = in_sizes[1] / 2;    // 1600000
    const int* src = ei;
    const int* dst = ei + E;

    float* out  = (float*)d_out;
    float* xrec = out;                       // [n,64]
    float* z    = out + (size_t)n * 64;      // [n,32]

    char* ws = (char*)d_ws;
    size_t off = 0;
    float* dinv    = (float*)(ws + off); off += align256((size_t)n * 4);
    int*   cnt     = (int*)(ws + off);   off += align256((size_t)n * 4);
    int*   row_ptr = (int*)(ws + off);   off += align256((size_t)(n + 1) * 4);
    int*   cur     = (int*)(ws + off);   off += align256((size_t)n * 4);
    int2*  csr     = (int2*)(ws + off);  off += align256((size_t)E * 8);
    float* buf1    = (float*)(ws + off); off += align256((size_t)n * 64 * 4);
    float* buf2    = (float*)(ws + off); off += align256((size_t)n * 64 * 4);

    const int B = 256;
    const int edgeGrid = (E + B - 1) / B;
    constexpr int NPW = 8;                              // nodes per wave
    const int fGrid = (n + NPW * 4 - 1) / (NPW * 4);    // 4 waves per block

    // ---- CSR build ----
    hipMemsetAsync(cnt, 0, (size_t)n * 4, stream);
    hist_kernel<<<edgeGrid, B, 0, stream>>>(dst, E, cnt);
    dinv_kernel<<<(n + B - 1) / B, B, 0, stream>>>(cnt, dinv, n);
    scan_kernel<<<1, 1024, 0, stream>>>(cnt, row_ptr, n);
    hipMemsetAsync(cur, 0, (size_t)n * 4, stream);
    scatter_kernel<<<edgeGrid, B, 0, stream>>>(src, dst, E, row_ptr, cur, dinv, csr);

    // ---- Layer 1: (A x) W1 + b1, relu -> buf2 ----
    fused_layer2<64, 64, true, true, NPW><<<fGrid, B, 0, stream>>>(
        x, W1, b1, row_ptr, csr, dinv, buf2, n);
    // ---- Layer 2: -> buf1 ----
    fused_layer2<64, 64, true, true, NPW><<<fGrid, B, 0, stream>>>(
        buf2, W2, b2, row_ptr, csr, dinv, buf1, n);
    // ---- Layer 3: mm = buf1 @ W3 (64->32) -> buf2, then A mm + b3 -> z ----
    matmul_kernel<64, 32><<<(n + 3) / 4, B, 0, stream>>>(buf1, W3, buf2, n);
    fused_layer2<32, 32, false, false, NPW><<<fGrid, B, 0, stream>>>(
        buf2, nullptr, b3, row_ptr, csr, dinv, z, n);
    // ---- Layer 4: (A z) W4 + b4, relu -> buf1 (aggregate at 32 wide) ----
    fused_layer2<32, 64, true, true, NPW><<<fGrid, B, 0, stream>>>(
        z, W4, b4, row_ptr, csr, dinv, buf1, n);
    // ---- Layer 5: -> buf2 ----
    fused_layer2<64, 64, true, true, NPW><<<fGrid, B, 0, stream>>>(
        buf1, W5, b5, row_ptr, csr, dinv, buf2, n);
    // ---- Layer 6 (no relu) -> xrec ----
    fused_layer2<64, 64, false, true, NPW><<<fGrid, B, 0, stream>>>(
        buf2, W6, b6, row_ptr, csr, dinv, xrec, n);
}

// Round 7
// 677.794 us; speedup vs baseline: 5.1585x; 1.3470x over previous
//
#include <hip/hip_runtime.h>

// GCN autoencoder, fp32, CSR gather-based.
// R5 (resubmitted after broker timeout): all layers are a single fused kernel
// (aggregate at K-wide, epilogue matvec with W columns in registers). Masked
// full-width edge batches (no serial remainder). Multi-block scan for CSR build.

static inline size_t align256(size_t x) { return (x + 255) & ~(size_t)255; }

__global__ void hist_kernel(const int* __restrict__ dst, int E, int* __restrict__ cnt) {
    int e = blockIdx.x * blockDim.x + threadIdx.x;
    if (e < E) atomicAdd(&cnt[dst[e]], 1);
}

__global__ void dinv_kernel(const int* __restrict__ cnt, float* __restrict__ dinv, int n) {
    int i = blockIdx.x * blockDim.x + threadIdx.x;
    if (i < n) dinv[i] = rsqrtf((float)cnt[i] + 1.0f);  // +1 self loop
}

// Per-block inclusive scan over 1024 elems; writes local inclusive into
// row_ptr[idx+1] and block total into bsum[blockIdx].
__global__ void scan_block_kernel(const int* __restrict__ cnt, int* __restrict__ row_ptr,
                                  int* __restrict__ bsum, int n) {
    __shared__ int wsum[16];
    int tid = threadIdx.x, lane = tid & 63, wv = tid >> 6;
    int idx = blockIdx.x * 1024 + tid;
    int x = (idx < n) ? cnt[idx] : 0;
#pragma unroll
    for (int off = 1; off < 64; off <<= 1) {
        int t = __shfl_up(x, off, 64);
        if (lane >= off) x += t;
    }
    if (lane == 63) wsum[wv] = x;
    __syncthreads();
    if (wv == 0 && lane < 16) {
        int s = wsum[lane];
#pragma unroll
        for (int off = 1; off < 16; off <<= 1) {
            int t = __shfl_up(s, off, 16);
            if ((lane & 15) >= off) s += t;
        }
        wsum[lane] = s;
    }
    __syncthreads();
    int incl = ((wv == 0) ? 0 : wsum[wv - 1]) + x;
    if (idx < n) row_ptr[idx + 1] = incl;
    if (tid == 1023) bsum[blockIdx.x] = incl;
}

// Single block scans the (<=1024) block sums in place (inclusive).
__global__ void scan_sums_kernel(int* __restrict__ bsum, int nb) {
    __shared__ int wsum[16];
    int tid = threadIdx.x, lane = tid & 63, wv = tid >> 6;
    int x = (tid < nb) ? bsum[tid] : 0;
#pragma unroll
    for (int off = 1; off < 64; off <<= 1) {
        int t = __shfl_up(x, off, 64);
        if (lane >= off) x += t;
    }
    if (lane == 63) wsum[wv] = x;
    __syncthreads();
    if (wv == 0 && lane < 16) {
        int s = wsum[lane];
#pragma unroll
        for (int off = 1; off < 16; off <<= 1) {
            int t = __shfl_up(s, off, 16);
            if ((lane & 15) >= off) s += t;
        }
        wsum[lane] = s;
    }
    __syncthreads();
    int incl = ((wv == 0) ? 0 : wsum[wv - 1]) + x;
    if (tid < nb) bsum[tid] = incl;
}

__global__ void add_off_kernel(int* __restrict__ row_ptr, const int* __restrict__ bsum, int n) {
    int idx = blockIdx.x * blockDim.x + threadIdx.x;
    if (idx >= n) return;
    int b = idx >> 10;
    if (b > 0) row_ptr[idx + 1] += bsum[b - 1];
    if (idx == 0) row_ptr[0] = 0;
}

__global__ void scatter_kernel(const int* __restrict__ src, const int* __restrict__ dst, int E,
                               const int* __restrict__ row_ptr, int* __restrict__ cur,
                               const float* __restrict__ dinv,
                               int2* __restrict__ csr) {
    int e = blockIdx.x * blockDim.x + threadIdx.x;
    if (e >= E) return;
    int s = src[e], d = dst[e];
    int pos = row_ptr[d] + atomicAdd(&cur[d], 1);
    csr[pos] = make_int2(s, __float_as_int(dinv[s] * dinv[d]));
}

// Fused GCN layer: out[i] = act( agg_K(in)[i] @ W (K->M) + b ).
// Edge loop: masked full-width batches, 4 records + 4 float4 gathers in flight.
// Epilogue: W columns in registers, aggregated row staged via per-wave LDS.
template <int K, int M, bool RELU, int NPW>
__global__ void __launch_bounds__(256) fused_layer2(
        const float* __restrict__ in, const float* __restrict__ W,
        const float* __restrict__ bias,
        const int* __restrict__ row_ptr, const int2* __restrict__ csr,
        const float* __restrict__ dinv,
        float* __restrict__ out, int n) {
    constexpr int LPR = K / 4;        // lanes per row (float4 cols)
    constexpr int EPW = 64 / LPR;     // edges per wave-load
    constexpr int BATCH = 4 * EPW;    // edges per iteration
    __shared__ alignas(16) float aS[4][K + 4];

    const int wv = threadIdx.x >> 6, lane = threadIdx.x & 63;
    const int g = lane / LPR, sub = lane % LPR;
    const float4* in4 = (const float4*)in;

    // per-wave W column + bias (amortized over NPW nodes)
    const int j = lane & (M - 1);
    float wcol[K];
#pragma unroll
    for (int k = 0; k < K; ++k) wcol[k] = W[k * M + j];
    const float br = bias[j];

    const int wave_id = blockIdx.x * 4 + wv;
    const int i_lo = wave_id * NPW;
    const int i_hi = min(i_lo + NPW, n);

    for (int i = i_lo; i < i_hi; ++i) {
        const int beg = row_ptr[i], end = row_ptr[i + 1];
        float4 acc = make_float4(0.f, 0.f, 0.f, 0.f);
        if (g == 0) {  // self-loop term, counted once after butterfly
            float di = dinv[i];
            float w2 = di * di;
            float4 v = in4[(size_t)i * LPR + sub];
            acc = make_float4(v.x * w2, v.y * w2, v.z * w2, v.w * w2);
        }

        for (int e = beg; e < end; e += BATCH) {
            int i0 = e + 0 * EPW + g;
            int i1 = e + 1 * EPW + g;
            int i2 = e + 2 * EPW + g;
            int i3 = e + 3 * EPW + g;
            bool m0 = i0 < end, m1 = i1 < end, m2 = i2 < end, m3 = i3 < end;
            int2 r0 = csr[m0 ? i0 : beg];
            int2 r1 = csr[m1 ? i1 : beg];
            int2 r2 = csr[m2 ? i2 : beg];
            int2 r3 = csr[m3 ? i3 : beg];
            float4 v0 = in4[(size_t)r0.x * LPR + sub];
            float4 v1 = in4[(size_t)r1.x * LPR + sub];
            float4 v2 = in4[(size_t)r2.x * LPR + sub];
            float4 v3 = in4[(size_t)r3.x * LPR + sub];
            float w0 = m0 ? __int_as_float(r0.y) : 0.0f;
            float w1 = m1 ? __int_as_float(r1.y) : 0.0f;
            float w2 = m2 ? __int_as_float(r2.y) : 0.0f;
            float w3 = m3 ? __int_as_float(r3.y) : 0.0f;
            acc.x = fmaf(w0, v0.x, acc.x); acc.y = fmaf(w0, v0.y, acc.y);
            acc.z = fmaf(w0, v0.z, acc.z); acc.w = fmaf(w0, v0.w, acc.w);
            acc.x = fmaf(w1, v1.x, acc.x); acc.y = fmaf(w1, v1.y, acc.y);
            acc.z = fmaf(w1, v1.z, acc.z); acc.w = fmaf(w1, v1.w, acc.w);
            acc.x = fmaf(w2, v2.x, acc.x); acc.y = fmaf(w2, v2.y, acc.y);
            acc.z = fmaf(w2, v2.z, acc.z); acc.w = fmaf(w2, v2.w, acc.w);
            acc.x = fmaf(w3, v3.x, acc.x); acc.y = fmaf(w3, v3.y, acc.y);
            acc.z = fmaf(w3, v3.z, acc.z); acc.w = fmaf(w3, v3.w, acc.w);
        }

        // butterfly reduce across edge-groups
#pragma unroll
        for (int off = LPR; off < 64; off <<= 1) {
            acc.x += __shfl_xor(acc.x, off, 64);
            acc.y += __shfl_xor(acc.y, off, 64);
            acc.z += __shfl_xor(acc.z, off, 64);
            acc.w += __shfl_xor(acc.w, off, 64);
        }

        if (g == 0) *(float4*)&aS[wv][sub * 4] = acc;
        float ya = br, yb = 0.0f;   // two chains for ILP
#pragma unroll
        for (int s = 0; s < LPR; ++s) {
            float4 a = *(const float4*)&aS[wv][s * 4];
            ya = fmaf(a.x, wcol[4 * s + 0], ya);
            yb = fmaf(a.y, wcol[4 * s + 1], yb);
            ya = fmaf(a.z, wcol[4 * s + 2], ya);
            yb = fmaf(a.w, wcol[4 * s + 3], yb);
        }
        float y = ya + yb;
        if (RELU) y = fmaxf(y, 0.0f);
        if (lane < M) out[(size_t)i * M + lane] = y;
    }
}

extern "C" void kernel_launch(void* const* d_in, const int* in_sizes, int n_in,
                              void* d_out, int out_size, void* d_ws, size_t ws_size,
                              hipStream_t stream) {
    (void)n_in; (void)out_size; (void)ws_size;

    const float* x  = (const float*)d_in[0];
    const int*   ei = (const int*)d_in[1];
    const float* W1 = (const float*)d_in[2];  const float* b1 = (const float*)d_in[3];
    const float* W2 = (const float*)d_in[4];  const float* b2 = (const float*)d_in[5];
    const float* W3 = (const float*)d_in[6];  const float* b3 = (const float*)d_in[7];
    const float* W4 = (const float*)d_in[8];  const float* b4 = (const float*)d_in[9];
    const float* W5 = (const float*)d_in[10]; const float* b5 = (const float*)d_in[11];
    const float* W6 = (const float*)d_in[12]; const float* b6 = (const float*)d_in[13];

    const int n = in_sizes[0] / 64;   // 100000
    const int E = in_sizes[1] / 2;    // 1600000
    const int* src = ei;
    const int* dst = ei + E;

    float* out  = (float*)d_out;
    float* xrec = out;                       // [n,64]
    float* z    = out + (size_t)n * 64;      // [n,32]

    char* ws = (char*)d_ws;
    size_t off = 0;
    float* dinv    = (float*)(ws + off); off += align256((size_t)n * 4);
    int*   cnt     = (int*)(ws + off);   off += align256((size_t)n * 4);
    int*   row_ptr = (int*)(ws + off);   off += align256((size_t)(n + 1) * 4);
    int*   cur     = (int*)(ws + off);   off += align256((size_t)n * 4);
    int*   bsum    = (int*)(ws + off);   off += align256(1024 * 4);
    int2*  csr     = (int2*)(ws + off);  off += align256((size_t)E * 8);
    float* buf1    = (float*)(ws + off); off += align256((size_t)n * 64 * 4);
    float* buf2    = (float*)(ws + off); off += align256((size_t)n * 64 * 4);

    const int B = 256;
    const int edgeGrid = (E + B - 1) / B;
    const int nb = (n + 1023) / 1024;
    constexpr int NPW = 8;                              // nodes per wave
    const int fGrid = (n + NPW * 4 - 1) / (NPW * 4);    // 4 waves per block

    // ---- CSR build ----
    hipMemsetAsync(cnt, 0, (size_t)n * 4, stream);
    hist_kernel<<<edgeGrid, B, 0, stream>>>(dst, E, cnt);
    dinv_kernel<<<(n + B - 1) / B, B, 0, stream>>>(cnt, dinv, n);
    scan_block_kernel<<<nb, 1024, 0, stream>>>(cnt, row_ptr, bsum, n);
    scan_sums_kernel<<<1, 1024, 0, stream>>>(bsum, nb);
    add_off_kernel<<<(n + B - 1) / B, B, 0, stream>>>(row_ptr, bsum, n);
    hipMemsetAsync(cur, 0, (size_t)n * 4, stream);
    scatter_kernel<<<edgeGrid, B, 0, stream>>>(src, dst, E, row_ptr, cur, dinv, csr);

    // ---- Layer 1: relu((A x) W1 + b1) -> buf1 ----
    fused_layer2<64, 64, true, NPW><<<fGrid, B, 0, stream>>>(
        x, W1, b1, row_ptr, csr, dinv, buf1, n);
    // ---- Layer 2: -> buf2 ----
    fused_layer2<64, 64, true, NPW><<<fGrid, B, 0, stream>>>(
        buf1, W2, b2, row_ptr, csr, dinv, buf2, n);
    // ---- Layer 3: (A buf2) W3 + b3 (64->32, no relu) -> z ----
    fused_layer2<64, 32, false, NPW><<<fGrid, B, 0, stream>>>(
        buf2, W3, b3, row_ptr, csr, dinv, z, n);
    // ---- Layer 4: relu((A z) W4 + b4) (32->64) -> buf1 ----
    fused_layer2<32, 64, true, NPW><<<fGrid, B, 0, stream>>>(
        z, W4, b4, row_ptr, csr, dinv, buf1, n);
    // ---- Layer 5: -> buf2 ----
    fused_layer2<64, 64, true, NPW><<<fGrid, B, 0, stream>>>(
        buf1, W5, b5, row_ptr, csr, dinv, buf2, n);
    // ---- Layer 6 (no relu) -> xrec ----
    fused_layer2<64, 64, false, NPW><<<fGrid, B, 0, stream>>>(
        buf2, W6, b6, row_ptr, csr, dinv, xrec, n);
}

// Round 8
// 659.120 us; speedup vs baseline: 5.3046x; 1.0283x over previous
//
#include <hip/hip_runtime.h>

// GCN autoencoder, fp32, CSR gather-based.
// R7: dual-node interleaved edge loops (2 independent gather streams per wave,
// 8 gathers in flight), paired epilogue (W loaded once, used for both nodes).
// dinv folded into the block scan.

static inline size_t align256(size_t x) { return (x + 255) & ~(size_t)255; }

__global__ void hist_kernel(const int* __restrict__ dst, int E, int* __restrict__ cnt) {
    int e = blockIdx.x * blockDim.x + threadIdx.x;
    if (e < E) atomicAdd(&cnt[dst[e]], 1);
}

// Per-block inclusive scan over 1024 elems; also emits dinv = rsqrt(cnt+1).
__global__ void scan_block_kernel(const int* __restrict__ cnt, int* __restrict__ row_ptr,
                                  int* __restrict__ bsum, float* __restrict__ dinv, int n) {
    __shared__ int wsum[16];
    int tid = threadIdx.x, lane = tid & 63, wv = tid >> 6;
    int idx = blockIdx.x * 1024 + tid;
    int v = (idx < n) ? cnt[idx] : 0;
    if (idx < n) dinv[idx] = rsqrtf((float)v + 1.0f);  // +1 self loop
    int x = v;
#pragma unroll
    for (int off = 1; off < 64; off <<= 1) {
        int t = __shfl_up(x, off, 64);
        if (lane >= off) x += t;
    }
    if (lane == 63) wsum[wv] = x;
    __syncthreads();
    if (wv == 0 && lane < 16) {
        int s = wsum[lane];
#pragma unroll
        for (int off = 1; off < 16; off <<= 1) {
            int t = __shfl_up(s, off, 16);
            if ((lane & 15) >= off) s += t;
        }
        wsum[lane] = s;
    }
    __syncthreads();
    int incl = ((wv == 0) ? 0 : wsum[wv - 1]) + x;
    if (idx < n) row_ptr[idx + 1] = incl;
    if (tid == 1023) bsum[blockIdx.x] = incl;
}

// Single block scans the (<=1024) block sums in place (inclusive).
__global__ void scan_sums_kernel(int* __restrict__ bsum, int nb) {
    __shared__ int wsum[16];
    int tid = threadIdx.x, lane = tid & 63, wv = tid >> 6;
    int x = (tid < nb) ? bsum[tid] : 0;
#pragma unroll
    for (int off = 1; off < 64; off <<= 1) {
        int t = __shfl_up(x, off, 64);
        if (lane >= off) x += t;
    }
    if (lane == 63) wsum[wv] = x;
    __syncthreads();
    if (wv == 0 && lane < 16) {
        int s = wsum[lane];
#pragma unroll
        for (int off = 1; off < 16; off <<= 1) {
            int t = __shfl_up(s, off, 16);
            if ((lane & 15) >= off) s += t;
        }
        wsum[lane] = s;
    }
    __syncthreads();
    int incl = ((wv == 0) ? 0 : wsum[wv - 1]) + x;
    if (tid < nb) bsum[tid] = incl;
}

__global__ void add_off_kernel(int* __restrict__ row_ptr, const int* __restrict__ bsum, int n) {
    int idx = blockIdx.x * blockDim.x + threadIdx.x;
    if (idx >= n) return;
    int b = idx >> 10;
    if (b > 0) row_ptr[idx + 1] += bsum[b - 1];
    if (idx == 0) row_ptr[0] = 0;
}

__global__ void scatter_kernel(const int* __restrict__ src, const int* __restrict__ dst, int E,
                               const int* __restrict__ row_ptr, int* __restrict__ cur,
                               const float* __restrict__ dinv,
                               int2* __restrict__ csr) {
    int e = blockIdx.x * blockDim.x + threadIdx.x;
    if (e >= E) return;
    int s = src[e], d = dst[e];
    int pos = row_ptr[d] + atomicAdd(&cur[d], 1);
    csr[pos] = make_int2(s, __float_as_int(dinv[s] * dinv[d]));
}

// Fused GCN layer: out[i] = act( agg_K(in)[i] @ W (K->M) + b ).
// Two nodes per iteration: independent gather streams + paired epilogue.
template <int K, int M, bool RELU, int NPW>
__global__ void __launch_bounds__(256) fused_layer3(
        const float* __restrict__ in, const float* __restrict__ W,
        const float* __restrict__ bias,
        const int* __restrict__ row_ptr, const int2* __restrict__ csr,
        const float* __restrict__ dinv,
        float* __restrict__ out, int n) {
    constexpr int LPR = K / 4;        // lanes per row (float4 cols)
    constexpr int EPW = 64 / LPR;     // edges per wave-load
    constexpr int BATCH = 4 * EPW;    // edges per stream-iteration
    __shared__ alignas(16) float aS[4][2][K + 4];

    const int wv = threadIdx.x >> 6, lane = threadIdx.x & 63;
    const int g = lane / LPR, sub = lane % LPR;
    const float4* in4 = (const float4*)in;
    const int j = lane & (M - 1);
    const float br = bias[j];

    const int wave_id = blockIdx.x * 4 + wv;
    const int i_lo = wave_id * NPW;
    const int i_hi = min(i_lo + NPW, n);

    for (int i = i_lo; i < i_hi; i += 2) {
        const bool has_b = (i + 1) < i_hi;
        const int ib = has_b ? i + 1 : i;
        const int begA = row_ptr[i],  endA = row_ptr[i + 1];
        int begB = row_ptr[ib], endB = row_ptr[ib + 1];
        if (!has_b) endB = begB;     // stream B empty

        float4 accA = make_float4(0.f, 0.f, 0.f, 0.f);
        float4 accB = make_float4(0.f, 0.f, 0.f, 0.f);
        if (g == 0) {   // self-loop terms (counted once after butterfly)
            float da = dinv[i];
            float4 va = in4[(size_t)i * LPR + sub];
            float wa = da * da;
            accA = make_float4(va.x * wa, va.y * wa, va.z * wa, va.w * wa);
            float db = dinv[ib];
            float4 vb = in4[(size_t)ib * LPR + sub];
            float wb = db * db;
            accB = make_float4(vb.x * wb, vb.y * wb, vb.z * wb, vb.w * wb);
        }

        const int nA = (endA - begA + BATCH - 1) / BATCH;
        const int nB = (endB - begB + BATCH - 1) / BATCH;
        const int nb = nA > nB ? nA : nB;
        for (int t = 0; t < nb; ++t) {
            const int baseA = begA + t * BATCH;
            const int baseB = begB + t * BATCH;
            int a0 = baseA + 0 * EPW + g, a1 = baseA + 1 * EPW + g;
            int a2 = baseA + 2 * EPW + g, a3 = baseA + 3 * EPW + g;
            int b0 = baseB + 0 * EPW + g, b1 = baseB + 1 * EPW + g;
            int b2 = baseB + 2 * EPW + g, b3 = baseB + 3 * EPW + g;
            bool mA0 = a0 < endA, mA1 = a1 < endA, mA2 = a2 < endA, mA3 = a3 < endA;
            bool mB0 = b0 < endB, mB1 = b1 < endB, mB2 = b2 < endB, mB3 = b3 < endB;
            int2 rA0 = csr[mA0 ? a0 : begA];
            int2 rA1 = csr[mA1 ? a1 : begA];
            int2 rA2 = csr[mA2 ? a2 : begA];
            int2 rA3 = csr[mA3 ? a3 : begA];
            int2 rB0 = csr[mB0 ? b0 : begA];
            int2 rB1 = csr[mB1 ? b1 : begA];
            int2 rB2 = csr[mB2 ? b2 : begA];
            int2 rB3 = csr[mB3 ? b3 : begA];
            float4 vA0 = in4[(size_t)rA0.x * LPR + sub];
            float4 vA1 = in4[(size_t)rA1.x * LPR + sub];
            float4 vA2 = in4[(size_t)rA2.x * LPR + sub];
            float4 vA3 = in4[(size_t)rA3.x * LPR + sub];
            float4 vB0 = in4[(size_t)rB0.x * LPR + sub];
            float4 vB1 = in4[(size_t)rB1.x * LPR + sub];
            float4 vB2 = in4[(size_t)rB2.x * LPR + sub];
            float4 vB3 = in4[(size_t)rB3.x * LPR + sub];
            float wA0 = mA0 ? __int_as_float(rA0.y) : 0.0f;
            float wA1 = mA1 ? __int_as_float(rA1.y) : 0.0f;
            float wA2 = mA2 ? __int_as_float(rA2.y) : 0.0f;
            float wA3 = mA3 ? __int_as_float(rA3.y) : 0.0f;
            float wB0 = mB0 ? __int_as_float(rB0.y) : 0.0f;
            float wB1 = mB1 ? __int_as_float(rB1.y) : 0.0f;
            float wB2 = mB2 ? __int_as_float(rB2.y) : 0.0f;
            float wB3 = mB3 ? __int_as_float(rB3.y) : 0.0f;
            accA.x = fmaf(wA0, vA0.x, accA.x); accA.y = fmaf(wA0, vA0.y, accA.y);
            accA.z = fmaf(wA0, vA0.z, accA.z); accA.w = fmaf(wA0, vA0.w, accA.w);
            accB.x = fmaf(wB0, vB0.x, accB.x); accB.y = fmaf(wB0, vB0.y, accB.y);
            accB.z = fmaf(wB0, vB0.z, accB.z); accB.w = fmaf(wB0, vB0.w, accB.w);
            accA.x = fmaf(wA1, vA1.x, accA.x); accA.y = fmaf(wA1, vA1.y, accA.y);
            accA.z = fmaf(wA1, vA1.z, accA.z); accA.w = fmaf(wA1, vA1.w, accA.w);
            accB.x = fmaf(wB1, vB1.x, accB.x); accB.y = fmaf(wB1, vB1.y, accB.y);
            accB.z = fmaf(wB1, vB1.z, accB.z); accB.w = fmaf(wB1, vB1.w, accB.w);
            accA.x = fmaf(wA2, vA2.x, accA.x); accA.y = fmaf(wA2, vA2.y, accA.y);
            accA.z = fmaf(wA2, vA2.z, accA.z); accA.w = fmaf(wA2, vA2.w, accA.w);
            accB.x = fmaf(wB2, vB2.x, accB.x); accB.y = fmaf(wB2, vB2.y, accB.y);
            accB.z = fmaf(wB2, vB2.z, accB.z); accB.w = fmaf(wB2, vB2.w, accB.w);
            accA.x = fmaf(wA3, vA3.x, accA.x); accA.y = fmaf(wA3, vA3.y, accA.y);
            accA.z = fmaf(wA3, vA3.z, accA.z); accA.w = fmaf(wA3, vA3.w, accA.w);
            accB.x = fmaf(wB3, vB3.x, accB.x); accB.y = fmaf(wB3, vB3.y, accB.y);
            accB.z = fmaf(wB3, vB3.z, accB.z); accB.w = fmaf(wB3, vB3.w, accB.w);
        }

        // butterfly reduce across edge-groups (independent chains for A/B)
#pragma unroll
        for (int off = LPR; off < 64; off <<= 1) {
            accA.x += __shfl_xor(accA.x, off, 64);
            accB.x += __shfl_xor(accB.x, off, 64);
            accA.y += __shfl_xor(accA.y, off, 64);
            accB.y += __shfl_xor(accB.y, off, 64);
            accA.z += __shfl_xor(accA.z, off, 64);
            accB.z += __shfl_xor(accB.z, off, 64);
            accA.w += __shfl_xor(accA.w, off, 64);
            accB.w += __shfl_xor(accB.w, off, 64);
        }

        if (g == 0) {
            *(float4*)&aS[wv][0][sub * 4] = accA;
            *(float4*)&aS[wv][1][sub * 4] = accB;
        }
        float yA0 = br, yA1 = 0.0f, yB0 = br, yB1 = 0.0f;
#pragma unroll
        for (int s = 0; s < LPR; ++s) {
            float4 aA = *(const float4*)&aS[wv][0][s * 4];
            float4 aB = *(const float4*)&aS[wv][1][s * 4];
            float w0 = W[(4 * s + 0) * M + j];
            float w1 = W[(4 * s + 1) * M + j];
            float w2 = W[(4 * s + 2) * M + j];
            float w3 = W[(4 * s + 3) * M + j];
            yA0 = fmaf(aA.x, w0, yA0);  yB0 = fmaf(aB.x, w0, yB0);
            yA1 = fmaf(aA.y, w1, yA1);  yB1 = fmaf(aB.y, w1, yB1);
            yA0 = fmaf(aA.z, w2, yA0);  yB0 = fmaf(aB.z, w2, yB0);
            yA1 = fmaf(aA.w, w3, yA1);  yB1 = fmaf(aB.w, w3, yB1);
        }
        float yA = yA0 + yA1, yB = yB0 + yB1;
        if (RELU) { yA = fmaxf(yA, 0.0f); yB = fmaxf(yB, 0.0f); }
        if (lane < M) {
            out[(size_t)i * M + lane] = yA;
            if (has_b) out[(size_t)(i + 1) * M + lane] = yB;
        }
    }
}

extern "C" void kernel_launch(void* const* d_in, const int* in_sizes, int n_in,
                              void* d_out, int out_size, void* d_ws, size_t ws_size,
                              hipStream_t stream) {
    (void)n_in; (void)out_size; (void)ws_size;

    const float* x  = (const float*)d_in[0];
    const int*   ei = (const int*)d_in[1];
    const float* W1 = (const float*)d_in[2];  const float* b1 = (const float*)d_in[3];
    const float* W2 = (const float*)d_in[4];  const float* b2 = (const float*)d_in[5];
    const float* W3 = (const float*)d_in[6];  const float* b3 = (const float*)d_in[7];
    const float* W4 = (const float*)d_in[8];  const float* b4 = (const float*)d_in[9];
    const float* W5 = (const float*)d_in[10]; const float* b5 = (const float*)d_in[11];
    const float* W6 = (const float*)d_in[12]; const float* b6 = (const float*)d_in[13];

    const int n = in_sizes[0] / 64;   // 100000
    const int E = in_sizes[1] / 2;    // 1600000
    const int* src = ei;
    const int* dst = ei + E;

    float* out  = (float*)d_out;
    float* xrec = out;                       // [n,64]
    float* z    = out + (size_t)n * 64;      // [n,32]

    char* ws = (char*)d_ws;
    size_t off = 0;
    float* dinv    = (float*)(ws + off); off += align256((size_t)n * 4);
    int*   cnt     = (int*)(ws + off);   off += align256((size_t)n * 4);
    int*   row_ptr = (int*)(ws + off);   off += align256((size_t)(n + 1) * 4);
    int*   cur     = (int*)(ws + off);   off += align256((size_t)n * 4);
    int*   bsum    = (int*)(ws + off);   off += align256(1024 * 4);
    int2*  csr     = (int2*)(ws + off);  off += align256((size_t)E * 8);
    float* buf1    = (float*)(ws + off); off += align256((size_t)n * 64 * 4);
    float* buf2    = (float*)(ws + off); off += align256((size_t)n * 64 * 4);

    const int B = 256;
    const int edgeGrid = (E + B - 1) / B;
    const int nb = (n + 1023) / 1024;
    constexpr int NPW = 8;                              // nodes per wave
    const int fGrid = (n + NPW * 4 - 1) / (NPW * 4);    // 4 waves per block

    // ---- CSR build ----
    hipMemsetAsync(cnt, 0, (size_t)n * 4, stream);
    hist_kernel<<<edgeGrid, B, 0, stream>>>(dst, E, cnt);
    scan_block_kernel<<<nb, 1024, 0, stream>>>(cnt, row_ptr, bsum, dinv, n);
    scan_sums_kernel<<<1, 1024, 0, stream>>>(bsum, nb);
    add_off_kernel<<<(n + B - 1) / B, B, 0, stream>>>(row_ptr, bsum, n);
    hipMemsetAsync(cur, 0, (size_t)n * 4, stream);
    scatter_kernel<<<edgeGrid, B, 0, stream>>>(src, dst, E, row_ptr, cur, dinv, csr);

    // ---- Layer 1: relu((A x) W1 + b1) -> buf1 ----
    fused_layer3<64, 64, true, NPW><<<fGrid, B, 0, stream>>>(
        x, W1, b1, row_ptr, csr, dinv, buf1, n);
    // ---- Layer 2: -> buf2 ----
    fused_layer3<64, 64, true, NPW><<<fGrid, B, 0, stream>>>(
        buf1, W2, b2, row_ptr, csr, dinv, buf2, n);
    // ---- Layer 3: (A buf2) W3 + b3 (64->32, no relu) -> z ----
    fused_layer3<64, 32, false, NPW><<<fGrid, B, 0, stream>>>(
        buf2, W3, b3, row_ptr, csr, dinv, z, n);
    // ---- Layer 4: relu((A z) W4 + b4) (32->64) -> buf1 ----
    fused_layer3<32, 64, true, NPW><<<fGrid, B, 0, stream>>>(
        z, W4, b4, row_ptr, csr, dinv, buf1, n);
    // ---- Layer 5: -> buf2 ----
    fused_layer3<64, 64, true, NPW><<<fGrid, B, 0, stream>>>(
        buf1, W5, b5, row_ptr, csr, dinv, buf2, n);
    // ---- Layer 6 (no relu) -> xrec ----
    fused_layer3<64, 64, false, NPW><<<fGrid, B, 0, stream>>>(
        buf2, W6, b6, row_ptr, csr, dinv, xrec, n);
}